// Round 14
// baseline (1454.704 us; speedup 1.0000x reference)
//
#include <hip/hip_runtime.h>

// SimpleLSTM persistent kernel, r13: single plain variant (no exotic attributes,
// no runtime API in kernel_launch — r12's container failure implicates one of
// amdgpu_num_vgpr / hipFuncGetAttributes, so both are gone).
// Geometry forced by storage identity (W_hh f16 = 512KB on-CU):
//   1024 threads/WG x 1 gate-row/thread, 92 weight VGPRs (fits the 128 budget
//   the compiler always grants), KRREG=184, LDS tail 9 chunks = 144KB chunk-major
//   (0 bank conflicts, measured r7/r8/r11), 3KB LDS gate exchange.
// 256 WGs (one per batch element); 16 waves/CU; recurrence via 2 barriers/step.

typedef _Float16 h16;
typedef _Float16 h2_t __attribute__((ext_vector_type(2)));
typedef _Float16 h8_t __attribute__((ext_vector_type(8)));

#if defined(__has_builtin)
#  if __has_builtin(__builtin_amdgcn_fdot2)
#    define FDOT2(a, b, c) __builtin_amdgcn_fdot2((a), (b), (c), false)
#  endif
#endif
#ifndef FDOT2
__device__ __forceinline__ float fdot2_sw(h2_t a, h2_t b, float c) {
  return c + (float)a.x * (float)b.x + (float)a.y * (float)b.y;
}
#  define FDOT2(a, b, c) fdot2_sw((a), (b), (c))
#endif

__device__ __forceinline__ float fast_sigmoid(float x) {
  return __builtin_amdgcn_rcpf(1.0f + __builtin_amdgcn_exp2f(-1.44269504f * x));
}
__device__ __forceinline__ float fast_tanh(float x) {
  return 1.0f - 2.0f * __builtin_amdgcn_rcpf(1.0f + __builtin_amdgcn_exp2f(2.88539008f * x));
}

union V8 { h8_t v; h2_t p[4]; };

#define NSTEPS 512
#define KR1K 184                  // k-range in VGPRs per row (92 h2 regs)
#define RC2  (KR1K / 8)           // 23 register chunks of 8 halfs
#define LC2  ((256 - KR1K) / 8)   // 9 LDS chunks of 8 halfs

__global__ void __launch_bounds__(1024, 1) lstm_1k(
    const float* __restrict__ X, const float* __restrict__ W_ih,
    const float* __restrict__ W_hh, const float* __restrict__ b_ih,
    const float* __restrict__ b_hh, const float* __restrict__ W_dense,
    const float* __restrict__ b_dense, float* __restrict__ out) {
  // Chunk-major: wlds8[c][r] = halfs [KR1K+8c, KR1K+8c+8) of W_hh row r.
  // For fixed c, lane t reads wlds8[c][t] -> 64 lanes span 1024 contiguous B
  // -> conflict-free (verified SQ_LDS_BANK_CONFLICT == 0 on this layout).
  __shared__ h8_t wlds8[LC2][1024];  // 144 KiB
  __shared__ h8_t hbuf8[32];         // h_t as f16 (256 halfs)
  __shared__ float garr[768];        // f,g,o pre-activations at [j],[256+j],[512+j]
  __shared__ float red[4][3];        // dense-head wave partials

  const int t = threadIdx.x;  // 0..1023: owns stacked-gate row t
  const int b = blockIdx.x;   // batch element

  // ---------------- init: pack weights ----------------
  h2_t wreg[KR1K / 2];  // 92 VGPRs of f16 pairs
  {
    const float* wr = W_hh + (size_t)t * 256;
#pragma unroll
    for (int kk = 0; kk < RC2; ++kk) {
      float4 a = ((const float4*)wr)[kk * 2];
      float4 c4 = ((const float4*)wr)[kk * 2 + 1];
      h2_t w0; w0.x = (h16)a.x;  w0.y = (h16)a.y;
      h2_t w1; w1.x = (h16)a.z;  w1.y = (h16)a.w;
      h2_t w2; w2.x = (h16)c4.x; w2.y = (h16)c4.y;
      h2_t w3; w3.x = (h16)c4.z; w3.y = (h16)c4.w;
      wreg[kk * 4 + 0] = w0;
      wreg[kk * 4 + 1] = w1;
      wreg[kk * 4 + 2] = w2;
      wreg[kk * 4 + 3] = w3;
    }
    const float* wt = wr + KR1K;
#pragma unroll
    for (int c = 0; c < LC2; ++c) {
      float4 a = ((const float4*)wt)[c * 2];
      float4 d = ((const float4*)wt)[c * 2 + 1];
      h8_t w8;
      w8[0] = (h16)a.x; w8[1] = (h16)a.y; w8[2] = (h16)a.z; w8[3] = (h16)a.w;
      w8[4] = (h16)d.x; w8[5] = (h16)d.y; w8[6] = (h16)d.z; w8[7] = (h16)d.w;
      wlds8[c][t] = w8;
    }
  }
  h2_t wih[5];  // W_ih row t (F=10 -> 5 pairs)
  {
    const float* wr = W_ih + (size_t)t * 10;
#pragma unroll
    for (int p = 0; p < 5; ++p) {
      h2_t w; w.x = (h16)wr[2 * p]; w.y = (h16)wr[2 * p + 1];
      wih[p] = w;
    }
  }
  const float bias = b_ih[t] + b_hh[t];
  float wd0 = 0.f, wd1 = 0.f, wd2 = 0.f, bd = 0.f, c_state = 0.f;
  if (t < 256) {
    wd0 = W_dense[t]; wd1 = W_dense[256 + t]; wd2 = W_dense[512 + t];
    ((h16*)hbuf8)[t] = (h16)0.f;  // h0 = 0
  }
  if (t < 3) bd = b_dense[t];

  const float* Xb = X + (size_t)b * (NSTEPS * 10);
  float* outb = out + (size_t)b * (NSTEPS * 3);

  __syncthreads();

  // ---------------- time loop ----------------
  for (int step = 0; step < NSTEPS; ++step) {
    // Phase A: pre-activation for row t; 2 acc chains relax fdot2 latency.
    float acc[2]; acc[0] = bias; acc[1] = 0.f;
    {
      const float* xp = Xb + step * 10;
#pragma unroll
      for (int p = 0; p < 5; ++p) {
        h2_t xh; xh.x = (h16)xp[2 * p]; xh.y = (h16)xp[2 * p + 1];
        acc[0] = FDOT2(xh, wih[p], acc[0]);
      }
    }
    // register-resident k in [0,184)
#pragma unroll
    for (int kk = 0; kk < RC2; ++kk) {
      V8 u; u.v = hbuf8[kk];  // broadcast read
      const int pa = kk & 1;
#pragma unroll
      for (int p = 0; p < 4; ++p) acc[pa] = FDOT2(u.p[p], wreg[kk * 4 + p], acc[pa]);
    }
    // LDS-resident k in [184,256)
#pragma unroll
    for (int c = 0; c < LC2; ++c) {
      V8 u; u.v = hbuf8[RC2 + c];  // broadcast read
      V8 w; w.v = wlds8[c][t];     // 64 lanes x 16B contiguous
      const int pa = c & 1;
#pragma unroll
      for (int p = 0; p < 4; ++p) acc[pa] = FDOT2(u.p[p], w.p[p], acc[pa]);
    }
    const float g = acc[0] + acc[1];

    // Phase B: rows >=256 publish f,g,o; rows <256 (i) finish the cell.
    if (t >= 256) garr[t - 256] = g;  // f_j at [j], g_j at [256+j], o_j at [512+j]
    __syncthreads();  // [1] garr visible; all hbuf reads of this step complete
    if (t < 256) {
      const float ig = fast_sigmoid(g);
      const float fg = fast_sigmoid(garr[t]);
      const float gg = fast_tanh(garr[256 + t]);
      const float og = fast_sigmoid(garr[512 + t]);
      c_state = fg * c_state + ig * gg;
      const float h = og * fast_tanh(c_state);
      ((h16*)hbuf8)[t] = (h16)h;  // safe: all readers passed barrier [1]
      // dense head: 3 dot products over the 256 hidden units
      float p0 = h * wd0, p1 = h * wd1, p2 = h * wd2;
#pragma unroll
      for (int m = 32; m > 0; m >>= 1) {
        p0 += __shfl_xor(p0, m);
        p1 += __shfl_xor(p1, m);
        p2 += __shfl_xor(p2, m);
      }
      if ((t & 63) == 0) {
        red[t >> 6][0] = p0; red[t >> 6][1] = p1; red[t >> 6][2] = p2;
      }
    }
    __syncthreads();  // [2] h_{t+1} + head partials visible
    if (t < 3) {
      outb[step * 3 + t] = red[0][t] + red[1][t] + red[2][t] + red[3][t] + bd;
    }
  }
}

extern "C" void kernel_launch(void* const* d_in, const int* in_sizes, int n_in,
                              void* d_out, int out_size, void* d_ws, size_t ws_size,
                              hipStream_t stream) {
  const float* X       = (const float*)d_in[0];
  const float* W_ih    = (const float*)d_in[1];
  const float* W_hh    = (const float*)d_in[2];
  const float* b_ih    = (const float*)d_in[3];
  const float* b_hh    = (const float*)d_in[4];
  const float* W_dense = (const float*)d_in[5];
  const float* b_dense = (const float*)d_in[6];
  lstm_1k<<<dim3(256), dim3(1024), 0, stream>>>(
      X, W_ih, W_hh, b_ih, b_hh, W_dense, b_dense, (float*)d_out);
}